// Round 1
// baseline (1987.112 us; speedup 1.0000x reference)
//
#include <hip/hip_runtime.h>
#include <stdint.h>

#define S   128
#define NB  32
#define NC  256
#define DK  128

typedef __bf16 bf16x8 __attribute__((ext_vector_type(8)));
typedef float  f32x16 __attribute__((ext_vector_type(16)));
typedef unsigned int u32x4 __attribute__((ext_vector_type(4)));
static_assert(sizeof(bf16x8) == 16, "bf16x8 size");
static_assert(sizeof(u32x4) == 16, "u32x4 size");

// d_ws layout (float offsets). Total 2,670,592 floats = ~10.2 MB.
#define OFF_AL   0
#define OFF_P2   524288
#define OFF_P3   1044480
#define OFF_PS   1564672
#define OFF_PY   2084864
#define OFF_WT2  2605056
#define OFF_WT3  2621440
#define OFF_WT4  2637824
#define OFF_WT5  2654208

__device__ __forceinline__ float v_exp2(float x){ float r; asm("v_exp_f32 %0, %1" : "=v"(r) : "v"(x)); return r; }
__device__ __forceinline__ float v_rcp (float x){ float r; asm("v_rcp_f32 %0, %1" : "=v"(r) : "v"(x)); return r; }
// sigmoid(x) = 1/(1+2^(-x*log2e))
__device__ __forceinline__ float sigm(float x){ return v_rcp(1.0f + v_exp2(x * -1.4426950408889634f)); }
__device__ __forceinline__ uint32_t pkbf(float lo, float hi){
  uint32_t r; asm("v_cvt_pk_bf16_f32 %0, %1, %2" : "=v"(r) : "v"(lo), "v"(hi)); return r;
}

// ---------------- kernel 0: AL[b][t][j] = concat(e_emb, at_emb, a*ones50) @ W1 + b1 ----------------
__global__ __launch_bounds__(512) void k0_al(
    const int* __restrict__ e_data, const int* __restrict__ at_data,
    const float* __restrict__ a_data, const float* __restrict__ e_E,
    const float* __restrict__ at_E, const float* __restrict__ W1,
    const float* __restrict__ b1, float* __restrict__ ws)
{
  __shared__ float ein[32][128];
  __shared__ float atin[32][128];
  int b = blockIdx.x >> 2, q4 = blockIdx.x & 3, t0 = q4 * 32;
  for (int idx = threadIdx.x; idx < 32 * 128; idx += 512) {
    int r = idx >> 7, j = idx & 127;
    int ev  = e_data [b * S + t0 + r];
    int atv = at_data[b * S + t0 + r];
    ein [r][j] = e_E [ev  * DK + j];
    atin[r][j] = at_E[atv * DK + j];
  }
  __syncthreads();
  int j = threadIdx.x & 127, tq = threadIdx.x >> 7;
  float w1s = 0.f;
  for (int d = 0; d < 50; ++d) w1s += W1[(256 + d) * DK + j];
  float acc[8];
#pragma unroll
  for (int u = 0; u < 8; ++u) {
    int t = t0 + tq * 8 + u;
    acc[u] = b1[j] + a_data[b * S + t] * w1s;
  }
  for (int k = 0; k < 128; ++k) {
    float w = W1[k * DK + j];
#pragma unroll
    for (int u = 0; u < 8; ++u) acc[u] += ein[tq * 8 + u][k] * w;
  }
  for (int k = 0; k < 128; ++k) {
    float w = W1[(128 + k) * DK + j];
#pragma unroll
    for (int u = 0; u < 8; ++u) acc[u] += atin[tq * 8 + u][k] * w;
  }
#pragma unroll
  for (int u = 0; u < 8; ++u)
    ws[OFF_AL + (b * S + t0 + tq * 8 + u) * DK + j] = acc[u];
}

// ---------------- kernel T: transpose the 4 per-step GEMV weight blocks into ws (f32) ----------------
__global__ __launch_bounds__(256) void kT_tr(
    const float* __restrict__ W2, const float* __restrict__ W3,
    const float* __restrict__ W4, const float* __restrict__ W5,
    float* __restrict__ ws)
{
  int idx = blockIdx.x * 256 + threadIdx.x;            // 0 .. 65535
  int m = idx >> 14, rem = idx & 16383, j = rem >> 7, k = rem & 127;
  float v; int dstoff;
  if      (m == 0) { v = W2[(384 + k) * DK + j]; dstoff = OFF_WT2; }
  else if (m == 1) { v = W3[(384 + k) * DK + j]; dstoff = OFF_WT3; }
  else if (m == 2) { v = W4[(128 + k) * DK + j]; dstoff = OFF_WT4; }
  else             { v = W5[(128 + k) * DK + j]; dstoff = OFF_WT5; }
  ws[dstoff + j * DK + k] = v;
}

// ---------------- kernel 1: carry-independent per-step preactivations ----------------
// pre2/pre3 = [learning_pre, it, learning] @ W2/W3 rows[0:384) + b
// preS = it @ W4 rows[256:384) + b4 ; preY = e_next @ W5 rows[0:128) + b5
__global__ __launch_bounds__(512) void k1_pre(
    const int* __restrict__ e_data, const int* __restrict__ it_data,
    const float* __restrict__ it_E, const float* __restrict__ e_E,
    const float* __restrict__ W2, const float* __restrict__ b2,
    const float* __restrict__ W3, const float* __restrict__ b3,
    const float* __restrict__ W4, const float* __restrict__ b4,
    const float* __restrict__ W5, const float* __restrict__ b5,
    float* __restrict__ ws)
{
  __shared__ float als[33][128];
  __shared__ float its[32][128];
  __shared__ float ens[32][128];
  int b = blockIdx.x >> 2, sh = blockIdx.x & 3, s0 = sh * 32;
  for (int idx = threadIdx.x; idx < 33 * 128; idx += 512) {
    int r = idx >> 7, j = idx & 127;
    int srow = s0 - 1 + r;
    als[r][j] = (srow >= 0) ? ws[OFF_AL + (b * S + srow) * DK + j] : 0.f;
  }
  for (int idx = threadIdx.x; idx < 32 * 128; idx += 512) {
    int r = idx >> 7, j = idx & 127;
    int itv = it_data[b * S + s0 + r];
    its[r][j] = it_E[itv * DK + j];
    int sg = s0 + r + 1; if (sg > 127) sg = 127;
    int ev = e_data[b * S + sg];
    ens[r][j] = e_E[ev * DK + j];
  }
  __syncthreads();
  int j = threadIdx.x & 127, sq = threadIdx.x >> 7;
  float p2[8], p3[8], pS[8], pY[8];
#pragma unroll
  for (int u = 0; u < 8; ++u) { p2[u] = b2[j]; p3[u] = b3[j]; pS[u] = b4[j]; pY[u] = b5[j]; }
  for (int k = 0; k < 128; ++k) {
    float w2 = W2[k * DK + j], w3 = W3[k * DK + j];
#pragma unroll
    for (int u = 0; u < 8; ++u) { float v = als[sq * 8 + u][k]; p2[u] += v * w2; p3[u] += v * w3; }
  }
  for (int k = 0; k < 128; ++k) {
    float w2 = W2[(128 + k) * DK + j], w3 = W3[(128 + k) * DK + j], w4 = W4[(256 + k) * DK + j];
#pragma unroll
    for (int u = 0; u < 8; ++u) { float v = its[sq * 8 + u][k]; p2[u] += v * w2; p3[u] += v * w3; pS[u] += v * w4; }
  }
  for (int k = 0; k < 128; ++k) {
    float w2 = W2[(256 + k) * DK + j], w3 = W3[(256 + k) * DK + j];
#pragma unroll
    for (int u = 0; u < 8; ++u) { float v = als[sq * 8 + u + 1][k]; p2[u] += v * w2; p3[u] += v * w3; }
  }
  for (int k = 0; k < 128; ++k) {
    float w5 = W5[k * DK + j];
#pragma unroll
    for (int u = 0; u < 8; ++u) pY[u] += ens[sq * 8 + u][k] * w5;
  }
#pragma unroll
  for (int u = 0; u < 8; ++u) {
    int s = s0 + sq * 8 + u;
    if (s < 127) {
      int o = (b * 127 + s) * DK + j;
      ws[OFF_P2 + o] = p2[u]; ws[OFF_P3 + o] = p3[u];
      ws[OFF_PS + o] = pS[u]; ws[OFF_PY + o] = pY[u];
    }
  }
}

// ---------------- main recurrent kernel: 1 block per batch row ----------------
// wave (cg,jg): cg in 0..3 owns c rows [64cg,64cg+64); jg in 0..1 owns j cols [64jg,64jg+64)
// h master in f32 acc layout: hm[ci][ji][r], c = 64cg+32ci+(r&3)+8*(r>>2)+4*hi, j = 64jg+32ji+lo
__global__ __launch_bounds__(512, 2) void kmain(
    const int* __restrict__ e_data, const float* __restrict__ qmat,
    const float* __restrict__ W4, const float* __restrict__ h0,
    const float* __restrict__ ws, float* __restrict__ out)
{
  __shared__ char  hsb[65536];         // h as bf16, row-major [c][k], XOR-swizzled
  __shared__ float qbuf[2][256];
  __shared__ float htld[128];
  __shared__ float LGs[128];
  __shared__ float sbc[128];
  __shared__ float red[8][128];
  __shared__ float htp[4][128];
  __shared__ float yred[2];

  const int b = blockIdx.x;
  const int tid = threadIdx.x;
  const int lane = tid & 63, wv = tid >> 6;
  const int cg = wv >> 1, jg = wv & 1;
  const int lo = lane & 31, hi = lane >> 5;
  const int j = tid & 127, kq = tid >> 7;

  // B fragments of W4h (rows 0..127), register resident: bfr[ji][kk]
  u32x4 bfr[2][8];
#pragma unroll
  for (int ji = 0; ji < 2; ++ji) {
    int jc = jg * 64 + ji * 32 + lo;
#pragma unroll
    for (int kk = 0; kk < 8; ++kk) {
      float w[8];
#pragma unroll
      for (int e = 0; e < 8; ++e) w[e] = W4[(kk * 16 + hi * 8 + e) * DK + jc];
      u32x4 d;
      d[0] = pkbf(w[0], w[1]); d[1] = pkbf(w[2], w[3]);
      d[2] = pkbf(w[4], w[5]); d[3] = pkbf(w[6], w[7]);
      bfr[ji][kk] = d;
    }
  }

  // h0 -> master registers
  float hm[2][2][16];
#pragma unroll
  for (int ci = 0; ci < 2; ++ci)
#pragma unroll
    for (int ji = 0; ji < 2; ++ji)
#pragma unroll
      for (int r = 0; r < 16; ++r) {
        int row = (r & 3) + 8 * (r >> 2) + 4 * hi;
        hm[ci][ji][r] = h0[(cg * 64 + ci * 32 + row) * DK + jg * 64 + ji * 32 + lo];
      }

  auto pack_h = [&]() {
#pragma unroll
    for (int ci = 0; ci < 2; ++ci)
#pragma unroll
      for (int ji = 0; ji < 2; ++ji) {
        int jb2 = (jg * 64 + ji * 32 + (lo & ~1)) * 2;
#pragma unroll
        for (int rp = 0; rp < 8; ++rp) {
          float xa = hm[ci][ji][2 * rp], xb = hm[ci][ji][2 * rp + 1];
          float ya = __shfl_xor(xa, 1), yb = __shfl_xor(xb, 1);
          uint32_t pe = pkbf(xa, ya), po = pkbf(yb, xb);
          uint32_t val = (lane & 1) ? po : pe;
          int r = 2 * rp + (lane & 1);
          int row = (r & 3) + 8 * (r >> 2) + 4 * hi;
          int c = cg * 64 + ci * 32 + row;
          int addr = c * 256 + (jb2 ^ ((c & 15) << 4));
          *(uint32_t*)(hsb + addr) = val;
        }
      }
  };

  if (tid < 256) qbuf[0][tid] = qmat[e_data[b * S] * NC + tid];
  if (tid == 0) out[b * S] = 0.f;
  __syncthreads();

  // initial h_stage + h_tilde_init = sum_c q0[c] * h0[c,:]
  {
    float ht0[2] = {0.f, 0.f};
#pragma unroll
    for (int ci = 0; ci < 2; ++ci)
#pragma unroll
      for (int r = 0; r < 16; ++r) {
        int row = (r & 3) + 8 * (r >> 2) + 4 * hi;
        float qv = qbuf[0][cg * 64 + ci * 32 + row];
        ht0[0] += qv * hm[ci][0][r];
        ht0[1] += qv * hm[ci][1][r];
      }
#pragma unroll
    for (int ji = 0; ji < 2; ++ji) {
      float v = ht0[ji] + __shfl_xor(ht0[ji], 32);
      if (hi == 0) htp[cg][jg * 64 + ji * 32 + lo] = v;
    }
    pack_h();
  }
  __syncthreads();
  if (tid < 128) htld[j] = htp[0][j] + htp[1][j] + htp[2][j] + htp[3][j];
  __syncthreads();

#pragma unroll 1
  for (int s = 0; s < S - 1; ++s) {
    const float* qc = qbuf[s & 1];
    float* qn = qbuf[(s + 1) & 1];
    if (tid < 256) qn[tid] = qmat[e_data[b * S + s + 1] * NC + tid];
    float r2 = 0.f, r3 = 0.f, rS = 0.f, rY = 0.f;
    if (tid < 128) {
      int o = (b * 127 + s) * DK + j;
      r2 = ws[OFF_P2 + o]; r3 = ws[OFF_P3 + o];
      rS = ws[OFF_PS + o]; rY = ws[OFF_PY + o];
    }

    // big GEMM: pre[c,j] = h_bf16[c,:] @ W4h[:,j]
    f32x16 acc[2][2];
#pragma unroll
    for (int ci = 0; ci < 2; ++ci)
#pragma unroll
      for (int ji = 0; ji < 2; ++ji)
#pragma unroll
        for (int r = 0; r < 16; ++r) acc[ci][ji][r] = 0.f;
#pragma unroll
    for (int kk = 0; kk < 8; ++kk) {
      bf16x8 af[2];
#pragma unroll
      for (int ci = 0; ci < 2; ++ci) {
        int c = cg * 64 + ci * 32 + lo;
        int byt = c * 256 + (((kk * 16 + hi * 8) * 2) ^ ((c & 15) << 4));
        af[ci] = __builtin_bit_cast(bf16x8, *(const u32x4*)(hsb + byt));
      }
#pragma unroll
      for (int ci = 0; ci < 2; ++ci)
#pragma unroll
        for (int ji = 0; ji < 2; ++ji)
          acc[ci][ji] = __builtin_amdgcn_mfma_f32_32x32x16_bf16(
              af[ci], __builtin_bit_cast(bf16x8, bfr[ji][kk]), acc[ci][ji], 0, 0, 0);
    }

    // stage A: v2/v3 = pre2/pre3 + h_tilde @ W2d/W3d
    {
      float p2 = 0.f, p3 = 0.f;
      const float4* w2t = (const float4*)(ws + OFF_WT2 + j * DK + kq * 32);
      const float4* w3t = (const float4*)(ws + OFF_WT3 + j * DK + kq * 32);
#pragma unroll
      for (int i = 0; i < 8; ++i) {
        float4 a = w2t[i], bq = w3t[i];
        float h0v = htld[kq * 32 + i * 4 + 0], h1v = htld[kq * 32 + i * 4 + 1];
        float h2v = htld[kq * 32 + i * 4 + 2], h3v = htld[kq * 32 + i * 4 + 3];
        p2 += a.x * h0v + a.y * h1v + a.z * h2v + a.w * h3v;
        p3 += bq.x * h0v + bq.y * h1v + bq.z * h2v + bq.w * h3v;
      }
      red[kq][j] = p2; red[4 + kq][j] = p3;
    }
    __syncthreads(); // 1
    if (tid < 128) {
      float v2 = r2 + red[0][j] + red[1][j] + red[2][j] + red[3][j];
      float v3 = r3 + red[4][j] + red[5][j] + red[6][j] + red[7][j];
      // LG = sigmoid(v3) * (tanh(v2)+1)/2 = sigmoid(v3)*sigmoid(2*v2)
      LGs[j] = sigm(v3) * sigm(2.f * v2);
    }
    __syncthreads(); // 2
    // stage B: s_bc = preS + LG @ W4L
    {
      float pB = 0.f;
      const float4* w4t = (const float4*)(ws + OFF_WT4 + j * DK + kq * 32);
#pragma unroll
      for (int i = 0; i < 8; ++i) {
        float4 a = w4t[i];
        pB += a.x * LGs[kq * 32 + i * 4 + 0] + a.y * LGs[kq * 32 + i * 4 + 1]
            + a.z * LGs[kq * 32 + i * 4 + 2] + a.w * LGs[kq * 32 + i * 4 + 3];
      }
      red[kq][j] = pB;
    }
    __syncthreads(); // 3
    if (tid < 128) sbc[j] = rS + red[0][j] + red[1][j] + red[2][j] + red[3][j];
    __syncthreads(); // 4

    // elementwise: gamma_f = sigmoid(pre + s_bc); h = q_e*LG + gamma_f*h ; h_tilde partials
    {
      float sj0 = sbc[jg * 64 + lo], sj1 = sbc[jg * 64 + 32 + lo];
      float lg0 = LGs[jg * 64 + lo], lg1 = LGs[jg * 64 + 32 + lo];
      float ht[2] = {0.f, 0.f};
#pragma unroll
      for (int ci = 0; ci < 2; ++ci)
#pragma unroll
        for (int r = 0; r < 16; ++r) {
          int row = (r & 3) + 8 * (r >> 2) + 4 * hi;
          int c = cg * 64 + ci * 32 + row;
          float qe = qc[c], qnv = qn[c];
          {
            float g = sigm(acc[ci][0][r] + sj0);
            float hn = qe * lg0 + g * hm[ci][0][r];
            hm[ci][0][r] = hn; ht[0] += qnv * hn;
          }
          {
            float g = sigm(acc[ci][1][r] + sj1);
            float hn = qe * lg1 + g * hm[ci][1][r];
            hm[ci][1][r] = hn; ht[1] += qnv * hn;
          }
        }
#pragma unroll
      for (int ji = 0; ji < 2; ++ji) {
        float v = ht[ji] + __shfl_xor(ht[ji], 32);
        if (hi == 0) htp[cg][jg * 64 + ji * 32 + lo] = v;
      }
    }
    pack_h();
    __syncthreads(); // 5
    if (tid < 128) htld[j] = htp[0][j] + htp[1][j] + htp[2][j] + htp[3][j];
    __syncthreads(); // 6
    // stage C: y = mean_j sigmoid(preY + h_tilde_new @ W5h)
    {
      float pC = 0.f;
      const float4* w5t = (const float4*)(ws + OFF_WT5 + j * DK + kq * 32);
#pragma unroll
      for (int i = 0; i < 8; ++i) {
        float4 a = w5t[i];
        pC += a.x * htld[kq * 32 + i * 4 + 0] + a.y * htld[kq * 32 + i * 4 + 1]
            + a.z * htld[kq * 32 + i * 4 + 2] + a.w * htld[kq * 32 + i * 4 + 3];
      }
      red[kq][j] = pC;
    }
    __syncthreads(); // 7
    if (tid < 128) {
      float yv = sigm(rY + red[0][j] + red[1][j] + red[2][j] + red[3][j]);
#pragma unroll
      for (int off = 32; off >= 1; off >>= 1) yv += __shfl_xor(yv, off);
      if (lane == 0) yred[wv] = yv;
    }
    __syncthreads(); // 8
    if (tid == 0) out[b * S + s + 1] = (yred[0] + yred[1]) * (1.0f / 128.0f);
  }
}

extern "C" void kernel_launch(void* const* d_in, const int* in_sizes, int n_in,
                              void* d_out, int out_size, void* d_ws, size_t ws_size,
                              hipStream_t stream)
{
  (void)in_sizes; (void)n_in; (void)out_size; (void)ws_size;
  const int*   e_data  = (const int*)  d_in[0];
  const int*   at_data = (const int*)  d_in[1];
  const int*   it_data = (const int*)  d_in[2];
  const float* a_data  = (const float*)d_in[3];
  const float* qmat    = (const float*)d_in[4];
  const float* e_E     = (const float*)d_in[5];
  const float* at_E    = (const float*)d_in[6];
  const float* it_E    = (const float*)d_in[7];
  const float* W1 = (const float*)d_in[8];  const float* b1 = (const float*)d_in[9];
  const float* W2 = (const float*)d_in[10]; const float* b2 = (const float*)d_in[11];
  const float* W3 = (const float*)d_in[12]; const float* b3 = (const float*)d_in[13];
  const float* W4 = (const float*)d_in[14]; const float* b4 = (const float*)d_in[15];
  const float* W5 = (const float*)d_in[16]; const float* b5 = (const float*)d_in[17];
  const float* h0 = (const float*)d_in[18];
  float* ws  = (float*)d_ws;
  float* out = (float*)d_out;

  k0_al <<<128, 512, 0, stream>>>(e_data, at_data, a_data, e_E, at_E, W1, b1, ws);
  kT_tr <<<256, 256, 0, stream>>>(W2, W3, W4, W5, ws);
  k1_pre<<<128, 512, 0, stream>>>(e_data, it_data, it_E, e_E, W2, b2, W3, b3, W4, b4, W5, b5, ws);
  kmain <<<32, 512, 0, stream>>>(e_data, qmat, W4, h0, ws, out);
}

// Round 2
// 1572.151 us; speedup vs baseline: 1.2639x; 1.2639x over previous
//
#include <hip/hip_runtime.h>
#include <stdint.h>

#define S   128
#define NB  32
#define NC  256
#define DK  128

typedef __bf16 bf16x8 __attribute__((ext_vector_type(8)));
typedef float  f32x16 __attribute__((ext_vector_type(16)));
typedef unsigned int u32x4 __attribute__((ext_vector_type(4)));
static_assert(sizeof(bf16x8) == 16, "bf16x8 size");
static_assert(sizeof(u32x4) == 16, "u32x4 size");

// d_ws layout (float offsets). HT (h_tilde per step) reuses the AL region
// (AL is consumed by k1 before kmain writes HT). Total ~10.2 MB.
#define OFF_AL   0            // [32][128][128] all_learning; later [32][127][128] h_tilde
#define OFF_HT   OFF_AL
#define OFF_P2   524288
#define OFF_P3   1044480
#define OFF_PS   1564672
#define OFF_PY   2084864
#define OFF_WT2  2605056
#define OFF_WT3  2621440
#define OFF_WT4  2637824
#define OFF_WT5  2654208

__device__ __forceinline__ float v_exp2(float x){ float r; asm("v_exp_f32 %0, %1" : "=v"(r) : "v"(x)); return r; }
__device__ __forceinline__ float v_rcp (float x){ float r; asm("v_rcp_f32 %0, %1" : "=v"(r) : "v"(x)); return r; }
// sigmoid(x) = 1/(1+2^(-x*log2e))
__device__ __forceinline__ float sigm(float x){ return v_rcp(1.0f + v_exp2(x * -1.4426950408889634f)); }
__device__ __forceinline__ uint32_t pkbf(float lo, float hi){
  uint32_t r; asm("v_cvt_pk_bf16_f32 %0, %1, %2" : "=v"(r) : "v"(lo), "v"(hi)); return r;
}

// ---------------- kernel 0: AL[b][t][j] = concat(e_emb, at_emb, a*ones50) @ W1 + b1 ----------------
__global__ __launch_bounds__(512) void k0_al(
    const int* __restrict__ e_data, const int* __restrict__ at_data,
    const float* __restrict__ a_data, const float* __restrict__ e_E,
    const float* __restrict__ at_E, const float* __restrict__ W1,
    const float* __restrict__ b1, float* __restrict__ ws)
{
  __shared__ float ein[32][128];
  __shared__ float atin[32][128];
  int b = blockIdx.x >> 2, q4 = blockIdx.x & 3, t0 = q4 * 32;
  for (int idx = threadIdx.x; idx < 32 * 128; idx += 512) {
    int r = idx >> 7, j = idx & 127;
    int ev  = e_data [b * S + t0 + r];
    int atv = at_data[b * S + t0 + r];
    ein [r][j] = e_E [ev  * DK + j];
    atin[r][j] = at_E[atv * DK + j];
  }
  __syncthreads();
  int j = threadIdx.x & 127, tq = threadIdx.x >> 7;
  float w1s = 0.f;
  for (int d = 0; d < 50; ++d) w1s += W1[(256 + d) * DK + j];
  float acc[8];
#pragma unroll
  for (int u = 0; u < 8; ++u) {
    int t = t0 + tq * 8 + u;
    acc[u] = b1[j] + a_data[b * S + t] * w1s;
  }
  for (int k = 0; k < 128; ++k) {
    float w = W1[k * DK + j];
#pragma unroll
    for (int u = 0; u < 8; ++u) acc[u] += ein[tq * 8 + u][k] * w;
  }
  for (int k = 0; k < 128; ++k) {
    float w = W1[(128 + k) * DK + j];
#pragma unroll
    for (int u = 0; u < 8; ++u) acc[u] += atin[tq * 8 + u][k] * w;
  }
#pragma unroll
  for (int u = 0; u < 8; ++u)
    ws[OFF_AL + (b * S + t0 + tq * 8 + u) * DK + j] = acc[u];
}

// ---------------- kernel T: transpose the 4 per-step GEMV weight blocks into ws (f32) ----------------
__global__ __launch_bounds__(256) void kT_tr(
    const float* __restrict__ W2, const float* __restrict__ W3,
    const float* __restrict__ W4, const float* __restrict__ W5,
    float* __restrict__ ws)
{
  int idx = blockIdx.x * 256 + threadIdx.x;            // 0 .. 65535
  int m = idx >> 14, rem = idx & 16383, j = rem >> 7, k = rem & 127;
  float v; int dstoff;
  if      (m == 0) { v = W2[(384 + k) * DK + j]; dstoff = OFF_WT2; }
  else if (m == 1) { v = W3[(384 + k) * DK + j]; dstoff = OFF_WT3; }
  else if (m == 2) { v = W4[(128 + k) * DK + j]; dstoff = OFF_WT4; }
  else             { v = W5[(128 + k) * DK + j]; dstoff = OFF_WT5; }
  ws[dstoff + j * DK + k] = v;
}

// ---------------- kernel 1: carry-independent per-step preactivations ----------------
__global__ __launch_bounds__(512) void k1_pre(
    const int* __restrict__ e_data, const int* __restrict__ it_data,
    const float* __restrict__ it_E, const float* __restrict__ e_E,
    const float* __restrict__ W2, const float* __restrict__ b2,
    const float* __restrict__ W3, const float* __restrict__ b3,
    const float* __restrict__ W4, const float* __restrict__ b4,
    const float* __restrict__ W5, const float* __restrict__ b5,
    float* __restrict__ ws)
{
  __shared__ float als[33][128];
  __shared__ float its[32][128];
  __shared__ float ens[32][128];
  int b = blockIdx.x >> 2, sh = blockIdx.x & 3, s0 = sh * 32;
  for (int idx = threadIdx.x; idx < 33 * 128; idx += 512) {
    int r = idx >> 7, j = idx & 127;
    int srow = s0 - 1 + r;
    als[r][j] = (srow >= 0) ? ws[OFF_AL + (b * S + srow) * DK + j] : 0.f;
  }
  for (int idx = threadIdx.x; idx < 32 * 128; idx += 512) {
    int r = idx >> 7, j = idx & 127;
    int itv = it_data[b * S + s0 + r];
    its[r][j] = it_E[itv * DK + j];
    int sg = s0 + r + 1; if (sg > 127) sg = 127;
    int ev = e_data[b * S + sg];
    ens[r][j] = e_E[ev * DK + j];
  }
  __syncthreads();
  int j = threadIdx.x & 127, sq = threadIdx.x >> 7;
  float p2[8], p3[8], pS[8], pY[8];
#pragma unroll
  for (int u = 0; u < 8; ++u) { p2[u] = b2[j]; p3[u] = b3[j]; pS[u] = b4[j]; pY[u] = b5[j]; }
  for (int k = 0; k < 128; ++k) {
    float w2 = W2[k * DK + j], w3 = W3[k * DK + j];
#pragma unroll
    for (int u = 0; u < 8; ++u) { float v = als[sq * 8 + u][k]; p2[u] += v * w2; p3[u] += v * w3; }
  }
  for (int k = 0; k < 128; ++k) {
    float w2 = W2[(128 + k) * DK + j], w3 = W3[(128 + k) * DK + j], w4 = W4[(256 + k) * DK + j];
#pragma unroll
    for (int u = 0; u < 8; ++u) { float v = its[sq * 8 + u][k]; p2[u] += v * w2; p3[u] += v * w3; pS[u] += v * w4; }
  }
  for (int k = 0; k < 128; ++k) {
    float w2 = W2[(256 + k) * DK + j], w3 = W3[(256 + k) * DK + j];
#pragma unroll
    for (int u = 0; u < 8; ++u) { float v = als[sq * 8 + u + 1][k]; p2[u] += v * w2; p3[u] += v * w3; }
  }
  for (int k = 0; k < 128; ++k) {
    float w5 = W5[k * DK + j];
#pragma unroll
    for (int u = 0; u < 8; ++u) pY[u] += ens[sq * 8 + u][k] * w5;
  }
#pragma unroll
  for (int u = 0; u < 8; ++u) {
    int s = s0 + sq * 8 + u;
    if (s < 127) {
      int o = (b * 127 + s) * DK + j;
      ws[OFF_P2 + o] = p2[u]; ws[OFF_P3 + o] = p3[u];
      ws[OFF_PS + o] = pS[u]; ws[OFF_PY + o] = pY[u];
    }
  }
}

// ---------------- main recurrent kernel: 1 block per batch row, 4 barriers/step ----------------
// wave (cg,jg): cg 0..3 owns c in [64cg,64cg+64); jg 0..1 owns j in [64jg,64jg+64)
// h master f32 acc layout: hm[ci][ji][r]: c = 64cg+32ci+(r&3)+8(r>>2)+4hi, j = 64jg+32ji+lo
// hsb: double-buffered bf16 h [2][256 c][128 k], XOR-swizzled, 2x64KB
__global__ __attribute__((amdgpu_flat_work_group_size(512, 512), amdgpu_waves_per_eu(2, 2)))
void kmain(
    const int* __restrict__ e_data, const float* __restrict__ qmat,
    const float* __restrict__ W4, const float* __restrict__ h0,
    float* __restrict__ ws, float* __restrict__ out)
{
  __shared__ char  hsb[2][65536];
  __shared__ float qbuf[2][256];
  __shared__ float htld[128];
  __shared__ float LGs[128];
  __shared__ float sbc[128];
  __shared__ float htp[4][128];

  const int b = blockIdx.x;
  const int tid = threadIdx.x;
  const int lane = tid & 63, wv = tid >> 6;
  const int cg = wv >> 1, jg = wv & 1;
  const int lo = lane & 31, hi = lane >> 5;
  const int j = tid & 127;

  // B fragments of W4h (rows 0..127 of W4), register resident: bfr[ji][kk]
  u32x4 bfr[2][8];
#pragma unroll
  for (int ji = 0; ji < 2; ++ji) {
    int jc = jg * 64 + ji * 32 + lo;
#pragma unroll
    for (int kk = 0; kk < 8; ++kk) {
      float w[8];
#pragma unroll
      for (int e = 0; e < 8; ++e) w[e] = W4[(kk * 16 + hi * 8 + e) * DK + jc];
      u32x4 d;
      d[0] = pkbf(w[0], w[1]); d[1] = pkbf(w[2], w[3]);
      d[2] = pkbf(w[4], w[5]); d[3] = pkbf(w[6], w[7]);
      bfr[ji][kk] = d;
    }
  }

  // h0 -> master registers
  float hm[2][2][16];
#pragma unroll
  for (int ci = 0; ci < 2; ++ci)
#pragma unroll
    for (int ji = 0; ji < 2; ++ji)
#pragma unroll
      for (int r = 0; r < 16; ++r) {
        int row = (r & 3) + 8 * (r >> 2) + 4 * hi;
        hm[ci][ji][r] = h0[(cg * 64 + ci * 32 + row) * DK + jg * 64 + ji * 32 + lo];
      }

  if (tid < 256) qbuf[0][tid] = qmat[e_data[b * S] * NC + tid];
  __syncthreads();

  // initial pack into buffer 0 + h_tilde_init
  {
    float ht0[2] = {0.f, 0.f};
#pragma unroll
    for (int ci = 0; ci < 2; ++ci) {
#pragma unroll
      for (int r = 0; r < 16; ++r) {
        int row = (r & 3) + 8 * (r >> 2) + 4 * hi;
        float qv = qbuf[0][cg * 64 + ci * 32 + row];
        ht0[0] += qv * hm[ci][0][r];
        ht0[1] += qv * hm[ci][1][r];
      }
#pragma unroll
      for (int ji = 0; ji < 2; ++ji) {
        int jb2 = (jg * 64 + ji * 32 + (lo & ~1)) * 2;
#pragma unroll
        for (int rp = 0; rp < 8; ++rp) {
          float xa = hm[ci][ji][2 * rp], xb = hm[ci][ji][2 * rp + 1];
          float ya = __shfl_xor(xa, 1), yb = __shfl_xor(xb, 1);
          uint32_t pe = pkbf(xa, ya), po = pkbf(yb, xb);
          uint32_t val = (lane & 1) ? po : pe;
          int r = 2 * rp + (lane & 1);
          int row = (r & 3) + 8 * (r >> 2) + 4 * hi;
          int c = cg * 64 + ci * 32 + row;
          *(uint32_t*)(&hsb[0][0] + c * 256 + (jb2 ^ ((c & 15) << 4))) = val;
        }
      }
    }
#pragma unroll
    for (int ji = 0; ji < 2; ++ji) {
      float v = ht0[ji] + __shfl_xor(ht0[ji], 32);
      if (hi == 0) htp[cg][jg * 64 + ji * 32 + lo] = v;
    }
  }
  __syncthreads();
  if (tid < 128) htld[j] = htp[0][j] + htp[1][j] + htp[2][j] + htp[3][j];
  __syncthreads();

#pragma unroll 1
  for (int s = 0; s < S - 1; ++s) {
    const float* qc = qbuf[s & 1];
    float* qn = qbuf[(s + 1) & 1];
    if (tid < 256) qn[tid] = qmat[e_data[b * S + s + 1] * NC + tid];
    float r2 = 0.f, r3 = 0.f, rS = 0.f;
    if (tid < 128) {
      int o = (b * 127 + s) * DK + j;
      r2 = ws[OFF_P2 + o]; r3 = ws[OFF_P3 + o]; rS = ws[OFF_PS + o];
    }

    // stage A (waves 0-1): v2/v3 = pre + h_tilde @ W2d/W3d (full 128-dot, no reduce)
    if (tid < 128) {
      float p2 = r2, p3 = r3;
      const float4* w2t = (const float4*)(ws + OFF_WT2 + j * DK);
      const float4* w3t = (const float4*)(ws + OFF_WT3 + j * DK);
#pragma unroll
      for (int i = 0; i < 32; ++i) {
        float4 a = w2t[i], bq = w3t[i];
        float4 h4 = *(const float4*)&htld[4 * i];
        p2 += a.x * h4.x + a.y * h4.y + a.z * h4.z + a.w * h4.w;
        p3 += bq.x * h4.x + bq.y * h4.y + bq.z * h4.z + bq.w * h4.w;
      }
      // LG = sigmoid(v3) * (tanh(v2)+1)/2 = sigmoid(v3)*sigmoid(2*v2)
      LGs[j] = sigm(p3) * sigm(2.f * p2);
    }
    __syncthreads(); // B: LGs ready
    // stage B (waves 0-1): sbc = preS + LG @ W4L (full 128-dot)
    if (tid < 128) {
      float pB = rS;
      const float4* w4t = (const float4*)(ws + OFF_WT4 + j * DK);
#pragma unroll
      for (int i = 0; i < 32; ++i) {
        float4 a = w4t[i];
        float4 g4 = *(const float4*)&LGs[4 * i];
        pB += a.x * g4.x + a.y * g4.y + a.z * g4.z + a.w * g4.w;
      }
      sbc[j] = pB;
    }
    __syncthreads(); // C: sbc ready

    // MFMA + elementwise + pack, split by c-half (acc peak = 32 regs)
    const char* hrd = &hsb[s & 1][0];
    char*       hwr = &hsb[(s + 1) & 1][0];
    float sj0 = sbc[jg * 64 + lo], sj1 = sbc[jg * 64 + 32 + lo];
    float lg0 = LGs[jg * 64 + lo], lg1 = LGs[jg * 64 + 32 + lo];
    float ht[2] = {0.f, 0.f};
#pragma unroll
    for (int ci = 0; ci < 2; ++ci) {
      f32x16 acc0, acc1;
#pragma unroll
      for (int r = 0; r < 16; ++r) { acc0[r] = 0.f; acc1[r] = 0.f; }
      {
        int c = cg * 64 + ci * 32 + lo;
#pragma unroll
        for (int kk = 0; kk < 8; ++kk) {
          bf16x8 af = __builtin_bit_cast(bf16x8,
              *(const u32x4*)(hrd + c * 256 + (((kk * 32 + hi * 16)) ^ ((c & 15) << 4))));
          acc0 = __builtin_amdgcn_mfma_f32_32x32x16_bf16(af, __builtin_bit_cast(bf16x8, bfr[0][kk]), acc0, 0, 0, 0);
          acc1 = __builtin_amdgcn_mfma_f32_32x32x16_bf16(af, __builtin_bit_cast(bf16x8, bfr[1][kk]), acc1, 0, 0, 0);
        }
      }
#pragma unroll
      for (int r = 0; r < 16; ++r) {
        int row = (r & 3) + 8 * (r >> 2) + 4 * hi;
        int c = cg * 64 + ci * 32 + row;
        float qe = qc[c], qnv = qn[c];
        {
          float g = sigm(acc0[r] + sj0);
          float hn = qe * lg0 + g * hm[ci][0][r];
          hm[ci][0][r] = hn; ht[0] += qnv * hn;
        }
        {
          float g = sigm(acc1[r] + sj1);
          float hn = qe * lg1 + g * hm[ci][1][r];
          hm[ci][1][r] = hn; ht[1] += qnv * hn;
        }
      }
      // pack this c-half into the next buffer
#pragma unroll
      for (int ji = 0; ji < 2; ++ji) {
        int jb2 = (jg * 64 + ji * 32 + (lo & ~1)) * 2;
#pragma unroll
        for (int rp = 0; rp < 8; ++rp) {
          float xa = hm[ci][ji][2 * rp], xb = hm[ci][ji][2 * rp + 1];
          float ya = __shfl_xor(xa, 1), yb = __shfl_xor(xb, 1);
          uint32_t pe = pkbf(xa, ya), po = pkbf(yb, xb);
          uint32_t val = (lane & 1) ? po : pe;
          int r = 2 * rp + (lane & 1);
          int row = (r & 3) + 8 * (r >> 2) + 4 * hi;
          int c = cg * 64 + ci * 32 + row;
          *(uint32_t*)(hwr + c * 256 + (jb2 ^ ((c & 15) << 4))) = val;
        }
      }
    }
#pragma unroll
    for (int ji = 0; ji < 2; ++ji) {
      float v = ht[ji] + __shfl_xor(ht[ji], 32);
      if (hi == 0) htp[cg][jg * 64 + ji * 32 + lo] = v;
    }
    __syncthreads(); // D: htp + hsb[next] ready
    if (tid < 128) {
      float v = htp[0][j] + htp[1][j] + htp[2][j] + htp[3][j];
      htld[j] = v;
      ws[OFF_HT + (b * 127 + s) * DK + j] = v;   // for deferred y kernel
    }
    __syncthreads(); // E: htld ready
  }
}

// ---------------- kernel 2: deferred y = mean_j sigmoid(preY + h_tilde @ W5h) ----------------
__global__ __launch_bounds__(128) void k2_y(const float* __restrict__ ws, float* __restrict__ out)
{
  __shared__ float hts[8][128];
  __shared__ float part[2][8];
  int b = blockIdx.x >> 4, ch = blockIdx.x & 15, s0 = ch * 8;
  int j = threadIdx.x;
#pragma unroll
  for (int u = 0; u < 8; ++u) {
    int s = s0 + u;
    hts[u][j] = (s < 127) ? ws[OFF_HT + (b * 127 + s) * DK + j] : 0.f;
  }
  __syncthreads();
  float acc[8];
#pragma unroll
  for (int u = 0; u < 8; ++u) {
    int s = s0 + u;
    acc[u] = (s < 127) ? ws[OFF_PY + (b * 127 + s) * DK + j] : 0.f;
  }
  const float4* w5 = (const float4*)(ws + OFF_WT5 + j * DK);
#pragma unroll 8
  for (int i = 0; i < 32; ++i) {
    float4 w = w5[i];
#pragma unroll
    for (int u = 0; u < 8; ++u) {
      float4 h4 = *(const float4*)&hts[u][4 * i];
      acc[u] += w.x * h4.x + w.y * h4.y + w.z * h4.z + w.w * h4.w;
    }
  }
#pragma unroll
  for (int u = 0; u < 8; ++u) {
    float v = sigm(acc[u]);
#pragma unroll
    for (int off = 32; off >= 1; off >>= 1) v += __shfl_xor(v, off);
    if ((j & 63) == 0) part[j >> 6][u] = v;
  }
  __syncthreads();
  if (j < 8) {
    int s = s0 + j;
    if (s < 127) out[b * S + s + 1] = (part[0][j] + part[1][j]) * (1.0f / 128.0f);
  }
  if (j == 0 && ch == 0) out[b * S] = 0.f;
}

extern "C" void kernel_launch(void* const* d_in, const int* in_sizes, int n_in,
                              void* d_out, int out_size, void* d_ws, size_t ws_size,
                              hipStream_t stream)
{
  (void)in_sizes; (void)n_in; (void)out_size; (void)ws_size;
  const int*   e_data  = (const int*)  d_in[0];
  const int*   at_data = (const int*)  d_in[1];
  const int*   it_data = (const int*)  d_in[2];
  const float* a_data  = (const float*)d_in[3];
  const float* qmat    = (const float*)d_in[4];
  const float* e_E     = (const float*)d_in[5];
  const float* at_E    = (const float*)d_in[6];
  const float* it_E    = (const float*)d_in[7];
  const float* W1 = (const float*)d_in[8];  const float* b1 = (const float*)d_in[9];
  const float* W2 = (const float*)d_in[10]; const float* b2 = (const float*)d_in[11];
  const float* W3 = (const float*)d_in[12]; const float* b3 = (const float*)d_in[13];
  const float* W4 = (const float*)d_in[14]; const float* b4 = (const float*)d_in[15];
  const float* W5 = (const float*)d_in[16]; const float* b5 = (const float*)d_in[17];
  const float* h0 = (const float*)d_in[18];
  float* ws  = (float*)d_ws;
  float* out = (float*)d_out;

  k0_al <<<128, 512, 0, stream>>>(e_data, at_data, a_data, e_E, at_E, W1, b1, ws);
  kT_tr <<<256, 256, 0, stream>>>(W2, W3, W4, W5, ws);
  k1_pre<<<128, 512, 0, stream>>>(e_data, it_data, it_E, e_E, W2, b2, W3, b3, W4, b4, W5, b5, ws);
  kmain <<<32, 512, 0, stream>>>(e_data, qmat, W4, h0, ws, out);
  k2_y  <<<512, 128, 0, stream>>>(ws, out);
}